// Round 1
// baseline (952.193 us; speedup 1.0000x reference)
//
#include <hip/hip_runtime.h>

#define N_NODES  50000
#define N_EDGES  600000
#define DIM      128
#define N_LAYERS 5
#define N_GRAPHS 512

// ---------------------------------------------------------------- preprocess

__global__ void k_count(const int* __restrict__ dst, int* __restrict__ cnt) {
    int e = blockIdx.x * blockDim.x + threadIdx.x;
    if (e < N_EDGES) atomicAdd(&cnt[dst[e]], 1);
}

__global__ void k_dinv(const int* __restrict__ cnt, float* __restrict__ dinv) {
    int i = blockIdx.x * blockDim.x + threadIdx.x;
    if (i < N_NODES) dinv[i] = rsqrtf((float)(cnt[i] + 1));   // +1 self-loop
}

// single-block exclusive scan of cnt[0..N) -> row_ptr[0..N]
__global__ void k_scan(const int* __restrict__ cnt, int* __restrict__ row_ptr) {
    __shared__ int s[1024];
    const int T = 1024;
    int t = threadIdx.x;
    const int chunk = (N_NODES + T - 1) / T;   // 49
    int lo = t * chunk;
    int hi = lo + chunk; if (hi > N_NODES) hi = N_NODES;
    int sum = 0;
    for (int i = lo; i < hi; ++i) sum += cnt[i];
    s[t] = sum;
    __syncthreads();
    // Hillis-Steele inclusive scan
    for (int off = 1; off < T; off <<= 1) {
        int v = (t >= off) ? s[t - off] : 0;
        __syncthreads();
        s[t] += v;
        __syncthreads();
    }
    int pre = (t == 0) ? 0 : s[t - 1];
    for (int i = lo; i < hi; ++i) { row_ptr[i] = pre; pre += cnt[i]; }
    if (t == T - 1) row_ptr[N_NODES] = s[T - 1];
}

__global__ void k_copy_cursor(const int* __restrict__ row_ptr, int* __restrict__ cursor) {
    int i = blockIdx.x * blockDim.x + threadIdx.x;
    if (i < N_NODES) cursor[i] = row_ptr[i];
}

__global__ void k_fill(const int* __restrict__ src, const int* __restrict__ dst,
                       const float* __restrict__ dinv, int* __restrict__ cursor,
                       int* __restrict__ col, float* __restrict__ wnorm) {
    int e = blockIdx.x * blockDim.x + threadIdx.x;
    if (e < N_EDGES) {
        int d = dst[e], s = src[e];
        int pos = atomicAdd(&cursor[d], 1);
        col[pos]   = s;
        wnorm[pos] = dinv[s] * dinv[d];
    }
}

__global__ void k_granges(const int* __restrict__ batch,
                          unsigned* __restrict__ gstart, unsigned* __restrict__ gend) {
    int i = blockIdx.x * blockDim.x + threadIdx.x;
    if (i < N_NODES) {
        int g = batch[i];
        atomicMin(&gstart[g], (unsigned)i);
        atomicMax(&gend[g],   (unsigned)(i + 1));
    }
}

// ---------------------------------------------------------------- aggregation
// one wave per node, float2 per lane (64 lanes * 8B = 512B row)
__global__ __launch_bounds__(256) void k_agg(const float* __restrict__ hin,
                                             float* __restrict__ agg,
                                             const float* __restrict__ dinv,
                                             const int* __restrict__ row_ptr,
                                             const int* __restrict__ col,
                                             const float* __restrict__ wnorm) {
    int node = blockIdx.x * 4 + (threadIdx.x >> 6);
    if (node >= N_NODES) return;
    int lane = threadIdx.x & 63;
    const float2* __restrict__ hin2 = (const float2*)hin;
    float di = dinv[node];
    float2 v = hin2[(size_t)node * 64 + lane];
    float2 acc; acc.x = v.x * di * di; acc.y = v.y * di * di;   // self-loop
    int e0 = row_ptr[node], e1 = row_ptr[node + 1];
    for (int e = e0; e < e1; ++e) {
        int j   = col[e];
        float w = wnorm[e];
        float2 u = hin2[(size_t)j * 64 + lane];
        acc.x += u.x * w;
        acc.y += u.y * w;
    }
    ((float2*)agg)[(size_t)node * 64 + lane] = acc;
}

// ---------------------------------------------------------------- GEMM + bias + relu
// out[N,128] = relu(A[N,128] @ W[128,128] + b), fp32 vector FMA.
// 128-row block tile, 256 threads, 8x8 micro-tile. W fully in LDS (64KB),
// A staged transposed in 16-k chunks (Al[k][row], stride 132 -> 16B-aligned,
// 2-way-max bank aliasing which is free on CDNA4).
__global__ __launch_bounds__(256) void k_gemm(const float* __restrict__ A,
                                              const float* __restrict__ W,
                                              const float* __restrict__ bias,
                                              float* __restrict__ out) {
    __shared__ float Wl[DIM * DIM];      // [k][d]
    __shared__ float Al[16 * 132];       // [k][row] padded

    const int tid = threadIdx.x;
    const int rb  = blockIdx.x * 128;
    const int tc  = tid & 15;            // 16 col groups
    const int tr  = tid >> 4;            // 16 row groups

    // stage W (64KB), fully coalesced
    {
        const float4* Wg = (const float4*)W;
        float4* Ws4 = (float4*)Wl;
#pragma unroll
        for (int i = 0; i < 16; ++i) Ws4[tid + i * 256] = Wg[tid + i * 256];
    }

    float acc[8][8];
#pragma unroll
    for (int r = 0; r < 8; ++r)
#pragma unroll
        for (int c = 0; c < 8; ++c) acc[r][c] = 0.f;

    for (int kc = 0; kc < 8; ++kc) {
        __syncthreads();   // Al readers done (also fences W staging on kc=0)
        // stage A chunk transposed: Al[k][row], global k = kc*16+k
#pragma unroll
        for (int it = 0; it < 2; ++it) {
            int item = tid + it * 256;        // 0..511
            int r = item >> 2;                // row 0..127
            int f = item & 3;                 // float4 within the 16-k chunk
            int grow = rb + r;
            float4 v = make_float4(0.f, 0.f, 0.f, 0.f);
            if (grow < N_NODES)
                v = *(const float4*)&A[(size_t)grow * DIM + kc * 16 + f * 4];
            Al[(f * 4 + 0) * 132 + r] = v.x;
            Al[(f * 4 + 1) * 132 + r] = v.y;
            Al[(f * 4 + 2) * 132 + r] = v.z;
            Al[(f * 4 + 3) * 132 + r] = v.w;
        }
        __syncthreads();
#pragma unroll
        for (int k = 0; k < 16; ++k) {
            const float4 a0 = *(const float4*)&Al[k * 132 + tr * 8];
            const float4 a1 = *(const float4*)&Al[k * 132 + tr * 8 + 4];
            const float4 w0 = *(const float4*)&Wl[(kc * 16 + k) * DIM + tc * 4];
            const float4 w1 = *(const float4*)&Wl[(kc * 16 + k) * DIM + 64 + tc * 4];
            float a[8] = {a0.x, a0.y, a0.z, a0.w, a1.x, a1.y, a1.z, a1.w};
            float w[8] = {w0.x, w0.y, w0.z, w0.w, w1.x, w1.y, w1.z, w1.w};
#pragma unroll
            for (int r = 0; r < 8; ++r)
#pragma unroll
                for (int c = 0; c < 8; ++c) acc[r][c] += a[r] * w[c];
        }
    }

    float bl[8];
#pragma unroll
    for (int c = 0; c < 4; ++c) {
        bl[c]     = bias[tc * 4 + c];
        bl[4 + c] = bias[64 + tc * 4 + c];
    }
#pragma unroll
    for (int r = 0; r < 8; ++r) {
        int grow = rb + tr * 8 + r;
        if (grow < N_NODES) {
            float4 o0, o1;
            o0.x = fmaxf(acc[r][0] + bl[0], 0.f);
            o0.y = fmaxf(acc[r][1] + bl[1], 0.f);
            o0.z = fmaxf(acc[r][2] + bl[2], 0.f);
            o0.w = fmaxf(acc[r][3] + bl[3], 0.f);
            o1.x = fmaxf(acc[r][4] + bl[4], 0.f);
            o1.y = fmaxf(acc[r][5] + bl[5], 0.f);
            o1.z = fmaxf(acc[r][6] + bl[6], 0.f);
            o1.w = fmaxf(acc[r][7] + bl[7], 0.f);
            *(float4*)&out[(size_t)grow * DIM + tc * 4]      = o0;
            *(float4*)&out[(size_t)grow * DIM + 64 + tc * 4] = o1;
        }
    }
}

// ---------------------------------------------------------------- pooling
// batch is sorted -> each graph is a contiguous node range; no atomics.
__global__ void k_pool(const float* __restrict__ h,
                       const unsigned* __restrict__ gstart,
                       const unsigned* __restrict__ gend,
                       float* __restrict__ out, int layer) {
    int g = blockIdx.x;
    int d = threadIdx.x;                 // 128 threads
    unsigned s = gstart[g], e = gend[g];
    float sum = 0.f;
    if (s != 0xFFFFFFFFu)
        for (unsigned i = s; i < e; ++i) sum += h[(size_t)i * DIM + d];
    out[(size_t)g * (N_LAYERS * DIM) + layer * DIM + d] = sum;
}

// ---------------------------------------------------------------- launch

extern "C" void kernel_launch(void* const* d_in, const int* in_sizes, int n_in,
                              void* d_out, int out_size, void* d_ws, size_t ws_size,
                              hipStream_t stream) {
    const float* x    = (const float*)d_in[0];
    const int*   ei   = (const int*)d_in[1];       // [2, E]
    const int*   bat  = (const int*)d_in[2];
    const float* Ws   = (const float*)d_in[3];     // [5,128,128]
    const float* bs   = (const float*)d_in[4];     // [5,128]
    float*       outp = (float*)d_out;

    const int* srcp = ei;
    const int* dstp = ei + N_EDGES;

    char* base = (char*)d_ws;
    size_t off = 0;
    float*    hP      = (float*)(base + off); off += (size_t)N_NODES * DIM * 4;   // 25.6MB
    float*    hQ      = (float*)(base + off); off += (size_t)N_NODES * DIM * 4;   // 25.6MB
    float*    dinv    = (float*)(base + off); off += (size_t)N_NODES * 4;
    int*      cnt     = (int*)(base + off);   off += (size_t)N_NODES * 4;
    int*      row_ptr = (int*)(base + off);   off += 200016;                      // N+1 ints, padded
    int*      cursor  = (int*)(base + off);   off += (size_t)N_NODES * 4;
    int*      col     = (int*)(base + off);   off += (size_t)N_EDGES * 4;
    float*    wnorm   = (float*)(base + off); off += (size_t)N_EDGES * 4;
    unsigned* gstart  = (unsigned*)(base + off); off += 2048;
    unsigned* gend    = (unsigned*)(base + off); off += 2048;

    hipMemsetAsync(cnt,    0,    (size_t)N_NODES * 4, stream);
    hipMemsetAsync(gstart, 0xFF, 2048, stream);
    hipMemsetAsync(gend,   0,    2048, stream);

    const int BE = (N_EDGES + 255) / 256;   // 2344
    const int BN = (N_NODES + 255) / 256;   // 196

    k_count<<<BE, 256, 0, stream>>>(dstp, cnt);
    k_dinv<<<BN, 256, 0, stream>>>(cnt, dinv);
    k_scan<<<1, 1024, 0, stream>>>(cnt, row_ptr);
    k_copy_cursor<<<BN, 256, 0, stream>>>(row_ptr, cursor);
    k_fill<<<BE, 256, 0, stream>>>(srcp, dstp, dinv, cursor, col, wnorm);
    k_granges<<<BN, 256, 0, stream>>>(bat, gstart, gend);

    const int BAGG  = (N_NODES + 3) / 4;     // 12500 blocks * 256 (4 nodes/block)
    const int BGEMM = (N_NODES + 127) / 128; // 391

    for (int l = 0; l < N_LAYERS; ++l) {
        const float* hin = (l == 0) ? x : hQ;
        k_agg<<<BAGG, 256, 0, stream>>>(hin, hP, dinv, row_ptr, col, wnorm);
        k_gemm<<<BGEMM, 256, 0, stream>>>(hP, Ws + (size_t)l * DIM * DIM,
                                          bs + (size_t)l * DIM, hQ);
        k_pool<<<N_GRAPHS, DIM, 0, stream>>>(hQ, gstart, gend, outp, l);
    }
}

// Round 2
// 589.808 us; speedup vs baseline: 1.6144x; 1.6144x over previous
//
#include <hip/hip_runtime.h>

#define N_NODES  50000
#define N_EDGES  600000
#define DIM      128
#define N_LAYERS 5
#define N_GRAPHS 512
#define NB       ((N_NODES + 255) / 256)   // 196 scan blocks

// ---------------------------------------------------------------- preprocess

__global__ void k_count(const int* __restrict__ dst, int* __restrict__ cnt) {
    int e = blockIdx.x * blockDim.x + threadIdx.x;
    if (e < N_EDGES) atomicAdd(&cnt[dst[e]], 1);
}

// per-256-block sums of cnt
__global__ __launch_bounds__(256) void k_bsum(const int* __restrict__ cnt,
                                              int* __restrict__ bsum) {
    __shared__ int ws[4];
    int i = blockIdx.x * 256 + threadIdx.x;
    int v = (i < N_NODES) ? cnt[i] : 0;
#pragma unroll
    for (int o = 32; o > 0; o >>= 1) v += __shfl_down(v, o, 64);
    if ((threadIdx.x & 63) == 0) ws[threadIdx.x >> 6] = v;
    __syncthreads();
    if (threadIdx.x == 0) bsum[blockIdx.x] = ws[0] + ws[1] + ws[2] + ws[3];
}

// exclusive scan of the 196 block sums (1 block)
__global__ void k_scan_bsum(const int* __restrict__ bsum, int* __restrict__ boff) {
    __shared__ int s[256];
    int t = threadIdx.x;
    int v = (t < NB) ? bsum[t] : 0;
    s[t] = v;
    __syncthreads();
    for (int o = 1; o < 256; o <<= 1) {
        int u = (t >= o) ? s[t - o] : 0;
        __syncthreads();
        s[t] += u;
        __syncthreads();
    }
    if (t < NB) boff[t] = s[t] - v;
}

// per-block scan -> row_ptr, cursor, dinv (fused)
__global__ __launch_bounds__(256) void k_rowptr(const int* __restrict__ cnt,
                                                const int* __restrict__ boff,
                                                int* __restrict__ row_ptr,
                                                int* __restrict__ cursor,
                                                float* __restrict__ dinv) {
    __shared__ int s[256];
    int t = threadIdx.x;
    int i = blockIdx.x * 256 + t;
    int v = (i < N_NODES) ? cnt[i] : 0;
    s[t] = v;
    __syncthreads();
    for (int o = 1; o < 256; o <<= 1) {
        int u = (t >= o) ? s[t - o] : 0;
        __syncthreads();
        s[t] += u;
        __syncthreads();
    }
    int excl = boff[blockIdx.x] + s[t] - v;
    if (i < N_NODES) {
        row_ptr[i] = excl;
        cursor[i]  = excl;
        dinv[i]    = rsqrtf((float)(v + 1));    // +1 self-loop
    } else if (i == N_NODES) {
        row_ptr[N_NODES] = excl;
    }
}

__global__ void k_fill(const int* __restrict__ src, const int* __restrict__ dst,
                       const float* __restrict__ dinv, int* __restrict__ cursor,
                       int* __restrict__ col, float* __restrict__ wnorm) {
    int e = blockIdx.x * blockDim.x + threadIdx.x;
    if (e < N_EDGES) {
        int d = dst[e], s = src[e];
        int pos = atomicAdd(&cursor[d], 1);
        col[pos]   = s;
        wnorm[pos] = dinv[s] * dinv[d];
    }
}

__global__ void k_granges(const int* __restrict__ batch,
                          unsigned* __restrict__ gstart, unsigned* __restrict__ gend) {
    int i = blockIdx.x * blockDim.x + threadIdx.x;
    if (i < N_NODES) {
        int g = batch[i];
        atomicMin(&gstart[g], (unsigned)i);
        atomicMax(&gend[g],   (unsigned)(i + 1));
    }
}

// ---------------------------------------------------------------- aggregation
// one wave per node, float2/lane (512B row); edge loop 4-way unrolled so 4
// independent row-gathers are in flight; e0/e1 scalarized (wave-uniform).
__global__ __launch_bounds__(256) void k_agg(const float* __restrict__ hin,
                                             float* __restrict__ agg,
                                             const float* __restrict__ dinv,
                                             const int* __restrict__ row_ptr,
                                             const int* __restrict__ col,
                                             const float* __restrict__ wnorm) {
    int node = blockIdx.x * 4 + (threadIdx.x >> 6);
    if (node >= N_NODES) return;
    int lane = threadIdx.x & 63;
    const float2* __restrict__ hin2 = (const float2*)hin + lane;
    float di = dinv[node];
    float2 v = hin2[(size_t)node * 64];
    float2 acc; acc.x = v.x * di * di; acc.y = v.y * di * di;   // self-loop
    int e0 = row_ptr[node], e1 = row_ptr[node + 1];
    e0 = __builtin_amdgcn_readfirstlane(e0);
    e1 = __builtin_amdgcn_readfirstlane(e1);
    int e = e0;
    for (; e + 4 <= e1; e += 4) {
        int   j0 = col[e],     j1 = col[e + 1], j2 = col[e + 2], j3 = col[e + 3];
        float w0 = wnorm[e],   w1 = wnorm[e+1], w2 = wnorm[e+2], w3 = wnorm[e+3];
        float2 u0 = hin2[(size_t)j0 * 64];
        float2 u1 = hin2[(size_t)j1 * 64];
        float2 u2 = hin2[(size_t)j2 * 64];
        float2 u3 = hin2[(size_t)j3 * 64];
        acc.x += u0.x * w0; acc.y += u0.y * w0;
        acc.x += u1.x * w1; acc.y += u1.y * w1;
        acc.x += u2.x * w2; acc.y += u2.y * w2;
        acc.x += u3.x * w3; acc.y += u3.y * w3;
    }
    for (; e < e1; ++e) {
        int j = col[e]; float w = wnorm[e];
        float2 u = hin2[(size_t)j * 64];
        acc.x += u.x * w; acc.y += u.y * w;
    }
    ((float2*)agg)[(size_t)node * 64 + lane] = acc;
}

// ---------------------------------------------------------------- GEMM + bias + relu
// out[N,128] = relu(A @ W + b). 64-row block tile, 256 threads, 8x4 micro-tile.
// W staged per 32-k chunk (16KB), A chunk transposed [k][row] (8.5KB) -> ~25KB
// LDS, 782 blocks (~3/CU), VALU-bound inner loop.
__global__ __launch_bounds__(256) void k_gemm(const float* __restrict__ A,
                                              const float* __restrict__ W,
                                              const float* __restrict__ bias,
                                              float* __restrict__ out) {
    __shared__ float Wl[32 * 128];   // [k][c]
    __shared__ float Al[32 * 68];    // [k][row], pad to 68 (16B-aligned reads)

    const int tid = threadIdx.x;
    const int rb  = blockIdx.x * 64;
    const int tc  = tid & 31;        // cols tc*4 .. tc*4+3
    const int tr  = tid >> 5;        // rows tr*8 .. tr*8+7

    float acc[8][4] = {};

    for (int kc = 0; kc < 4; ++kc) {
        __syncthreads();
        // stage W chunk (4096 floats = 4 float4/thread), coalesced
        {
            const float4* Wg = (const float4*)(W + kc * 32 * DIM);
            float4* Ws4 = (float4*)Wl;
#pragma unroll
            for (int i = 0; i < 4; ++i) Ws4[tid + i * 256] = Wg[tid + i * 256];
        }
        // stage A chunk transposed (64 rows x 32 k, 2 float4/thread)
#pragma unroll
        for (int it = 0; it < 2; ++it) {
            int item = tid + it * 256;       // 0..511
            int r = item >> 3;               // row 0..63
            int f = item & 7;                // float4 within 32-k chunk
            int grow = rb + r;
            float4 v = make_float4(0.f, 0.f, 0.f, 0.f);
            if (grow < N_NODES)
                v = *(const float4*)&A[(size_t)grow * DIM + kc * 32 + f * 4];
            Al[(f * 4 + 0) * 68 + r] = v.x;
            Al[(f * 4 + 1) * 68 + r] = v.y;
            Al[(f * 4 + 2) * 68 + r] = v.z;
            Al[(f * 4 + 3) * 68 + r] = v.w;
        }
        __syncthreads();
#pragma unroll
        for (int k = 0; k < 32; ++k) {
            float4 a0 = *(const float4*)&Al[k * 68 + tr * 8];
            float4 a1 = *(const float4*)&Al[k * 68 + tr * 8 + 4];
            float4 w  = *(const float4*)&Wl[k * DIM + tc * 4];
            float a[8] = {a0.x, a0.y, a0.z, a0.w, a1.x, a1.y, a1.z, a1.w};
#pragma unroll
            for (int r = 0; r < 8; ++r) {
                acc[r][0] += a[r] * w.x;
                acc[r][1] += a[r] * w.y;
                acc[r][2] += a[r] * w.z;
                acc[r][3] += a[r] * w.w;
            }
        }
    }

    float4 bv = *(const float4*)&bias[tc * 4];
#pragma unroll
    for (int r = 0; r < 8; ++r) {
        int grow = rb + tr * 8 + r;
        if (grow < N_NODES) {
            float4 o;
            o.x = fmaxf(acc[r][0] + bv.x, 0.f);
            o.y = fmaxf(acc[r][1] + bv.y, 0.f);
            o.z = fmaxf(acc[r][2] + bv.z, 0.f);
            o.w = fmaxf(acc[r][3] + bv.w, 0.f);
            *(float4*)&out[(size_t)grow * DIM + tc * 4] = o;
        }
    }
}

// ---------------------------------------------------------------- pooling
// batch sorted -> contiguous ranges; 256 threads/graph, 2-way row split.
__global__ __launch_bounds__(256) void k_pool(const float* __restrict__ h,
                                              const unsigned* __restrict__ gstart,
                                              const unsigned* __restrict__ gend,
                                              float* __restrict__ out, int layer) {
    __shared__ float red[128];
    int g = blockIdx.x;
    int d = threadIdx.x & 127;
    int half = threadIdx.x >> 7;
    unsigned s = gstart[g], e = gend[g];
    float sum = 0.f;
    if (s != 0xFFFFFFFFu)
        for (unsigned i = s + half; i < e; i += 2) sum += h[(size_t)i * DIM + d];
    if (half) red[d] = sum;
    __syncthreads();
    if (!half) out[(size_t)g * (N_LAYERS * DIM) + layer * DIM + d] = sum + red[d];
}

// ---------------------------------------------------------------- launch

extern "C" void kernel_launch(void* const* d_in, const int* in_sizes, int n_in,
                              void* d_out, int out_size, void* d_ws, size_t ws_size,
                              hipStream_t stream) {
    const float* x    = (const float*)d_in[0];
    const int*   ei   = (const int*)d_in[1];       // [2, E]
    const int*   bat  = (const int*)d_in[2];
    const float* Ws   = (const float*)d_in[3];     // [5,128,128]
    const float* bs   = (const float*)d_in[4];     // [5,128]
    float*       outp = (float*)d_out;

    const int* srcp = ei;
    const int* dstp = ei + N_EDGES;

    char* base = (char*)d_ws;
    size_t off = 0;
    float*    hP      = (float*)(base + off); off += (size_t)N_NODES * DIM * 4;
    float*    hQ      = (float*)(base + off); off += (size_t)N_NODES * DIM * 4;
    float*    dinv    = (float*)(base + off); off += (size_t)N_NODES * 4;
    int*      cnt     = (int*)(base + off);   off += (size_t)N_NODES * 4;
    int*      row_ptr = (int*)(base + off);   off += 200016;
    int*      cursor  = (int*)(base + off);   off += (size_t)N_NODES * 4;
    int*      col     = (int*)(base + off);   off += (size_t)N_EDGES * 4;
    float*    wnorm   = (float*)(base + off); off += (size_t)N_EDGES * 4;
    int*      bsum    = (int*)(base + off);   off += 1024;
    int*      boff    = (int*)(base + off);   off += 1024;
    unsigned* gstart  = (unsigned*)(base + off); off += 2048;
    unsigned* gend    = (unsigned*)(base + off); off += 2048;

    hipMemsetAsync(cnt,    0,    (size_t)N_NODES * 4, stream);
    hipMemsetAsync(gstart, 0xFF, 2048, stream);
    hipMemsetAsync(gend,   0,    2048, stream);

    const int BE = (N_EDGES + 255) / 256;   // 2344

    k_count<<<BE, 256, 0, stream>>>(dstp, cnt);
    k_bsum<<<NB, 256, 0, stream>>>(cnt, bsum);
    k_scan_bsum<<<1, 256, 0, stream>>>(bsum, boff);
    k_rowptr<<<NB, 256, 0, stream>>>(cnt, boff, row_ptr, cursor, dinv);
    k_fill<<<BE, 256, 0, stream>>>(srcp, dstp, dinv, cursor, col, wnorm);
    k_granges<<<NB, 256, 0, stream>>>(bat, gstart, gend);

    const int BAGG  = (N_NODES + 3) / 4;     // 12500
    const int BGEMM = (N_NODES + 63) / 64;   // 782

    for (int l = 0; l < N_LAYERS; ++l) {
        const float* hin = (l == 0) ? x : hQ;
        k_agg<<<BAGG, 256, 0, stream>>>(hin, hP, dinv, row_ptr, col, wnorm);
        k_gemm<<<BGEMM, 256, 0, stream>>>(hP, Ws + (size_t)l * DIM * DIM,
                                          bs + (size_t)l * DIM, hQ);
        k_pool<<<N_GRAPHS, 256, 0, stream>>>(hQ, gstart, gend, outp, l);
    }
}